// Round 1
// baseline (787.556 us; speedup 1.0000x reference)
//
#include <hip/hip_runtime.h>

typedef _Float16 half8 __attribute__((ext_vector_type(8)));
typedef _Float16 half4 __attribute__((ext_vector_type(4)));
typedef float f32x4 __attribute__((ext_vector_type(4)));

#define SCALE_F 0.17677669529663687f

// ---------------- prep: mask fp32->f16, rpb gather ----------------
// i in [0, 1048576): converts 4 mask floats and 1 rpb element (rpb[h][p], i = h*65536+p)
__global__ __launch_bounds__(256) void prep_kernel(
    const float* __restrict__ mask, const float* __restrict__ table,
    const int* __restrict__ rpi, _Float16* __restrict__ maskh,
    _Float16* __restrict__ rpbh)
{
    int i = blockIdx.x * 256 + threadIdx.x;
    float4 v = ((const float4*)mask)[i];
    half4 hv = { (_Float16)v.x, (_Float16)v.y, (_Float16)v.z, (_Float16)v.w };
    *(half4*)(maskh + (size_t)i * 4) = hv;
    int p = i & 65535, hh = i >> 16;
    rpbh[i] = (_Float16)table[rpi[p] * 16 + hh];
}

// ---------------- QKV projection GEMM (fp32 in, f16 scattered out) -----------
// which==0: inp=x, wgt=q_w(512), out -> Q region (scaled by 1/sqrt(32))
// which==1: inp=y, wgt=kv_w(1024), cols<512 -> K region, cols>=512 -> V region
// Output layout per region: [b][h][n][32] f16 (slice of 8192 elems per (b,h)).
__global__ __launch_bounds__(256) void proj_qkv(
    const float* __restrict__ inp, const float* __restrict__ wgt,
    const float* __restrict__ bias, _Float16* __restrict__ qout,
    _Float16* __restrict__ kout, _Float16* __restrict__ vout, int which)
{
    __shared__ __align__(16) _Float16 As[128 * 64];
    __shared__ __align__(16) _Float16 Ws[128 * 64];
    const int t = threadIdx.x;
    const int lane = t & 63, wave = t >> 6;
    const int ql = lane & 15, g = lane >> 4;
    const int ct = blockIdx.x, rt = blockIdx.y;
    const int wr = (wave >> 1) * 64, wc = (wave & 1) * 64;

    f32x4 acc[4][4] = {};

    const int srr = t >> 4;          // staging row sub-index 0..15
    const int sc4 = (t & 15) * 4;    // staging col (floats)
    for (int kk = 0; kk < 8; ++kk) {
        const int k0 = kk * 64;
#pragma unroll
        for (int p = 0; p < 8; ++p) {
            int rr = p * 16 + srr;
            int r = rt * 128 + rr;
            // strided input row: global row r=(b,n) -> source row b*512 + 2n
            size_t irow = ((size_t)(r >> 8) * 512 + (size_t)((r & 255) * 2)) * 512;
            float4 av = *(const float4*)(inp + irow + k0 + sc4);
            half4 ah = { (_Float16)av.x, (_Float16)av.y, (_Float16)av.z, (_Float16)av.w };
            int boff = rr * 128 + ((sc4 * 2) ^ ((rr & 7) << 4));  // XOR-swizzled
            *(half4*)((char*)As + boff) = ah;
            int wrow = ct * 128 + rr;
            float4 wv = *(const float4*)(wgt + (size_t)wrow * 512 + k0 + sc4);
            half4 wh = { (_Float16)wv.x, (_Float16)wv.y, (_Float16)wv.z, (_Float16)wv.w };
            *(half4*)((char*)Ws + boff) = wh;
        }
        __syncthreads();
#pragma unroll
        for (int kh = 0; kh < 2; ++kh) {
            half8 af[4], bf[4];
#pragma unroll
            for (int i = 0; i < 4; ++i) {
                int row = wr + i * 16 + ql;
                af[i] = *(const half8*)((const char*)As + row * 128 +
                        ((kh * 64 + g * 16) ^ ((ql & 7) << 4)));
            }
#pragma unroll
            for (int j = 0; j < 4; ++j) {
                int row = wc + j * 16 + ql;
                bf[j] = *(const half8*)((const char*)Ws + row * 128 +
                        ((kh * 64 + g * 16) ^ ((ql & 7) << 4)));
            }
#pragma unroll
            for (int i = 0; i < 4; ++i)
#pragma unroll
                for (int j = 0; j < 4; ++j)
                    acc[i][j] = __builtin_amdgcn_mfma_f32_16x16x32_f16(af[i], bf[j], acc[i][j], 0, 0, 0);
        }
        __syncthreads();
    }

    const float scale = (which == 0) ? SCALE_F : 1.0f;
#pragma unroll
    for (int j = 0; j < 4; ++j) {
        int c = ct * 128 + wc + j * 16 + ql;
        float bv = bias[c];
#pragma unroll
        for (int i = 0; i < 4; ++i) {
#pragma unroll
            for (int rr = 0; rr < 4; ++rr) {
                int r = rt * 128 + wr + i * 16 + g * 4 + rr;
                float val = (acc[i][j][rr] + bv) * scale;
                _Float16 hv = (_Float16)val;
                int b = r >> 8, n = r & 255;
                if (which == 0) {
                    int hh = c >> 5, d = c & 31;
                    qout[((size_t)(b * 16 + hh) * 256 + n) * 32 + d] = hv;
                } else if (c < 512) {
                    int hh = c >> 5, d = c & 31;
                    kout[((size_t)(b * 16 + hh) * 256 + n) * 32 + d] = hv;
                } else {
                    int c2 = c - 512, hh = c2 >> 5, d = c2 & 31;
                    vout[((size_t)(b * 16 + hh) * 256 + n) * 32 + d] = hv;
                }
            }
        }
    }
}

// ---------------- fused window attention, one block per (b,h) ----------------
// Swapped QK^T: S^T tile = mfma(A=K_frag, B=Q_frag) -> lane&15 = query,
// keys = (lane>>4)*4 + reg.  That C-fragment is directly the A-operand of
// 16x16x16 f16 MFMA for PV (k = (lane>>4)*4 + j), so no cross-lane repack.
__global__ __launch_bounds__(256) void attn_kernel(
    const _Float16* __restrict__ Q, const _Float16* __restrict__ K,
    const _Float16* __restrict__ V, const _Float16* __restrict__ rpbh,
    const _Float16* __restrict__ maskh, _Float16* __restrict__ pre)
{
    const int blk = blockIdx.x;
    const int b = blk >> 4, h = blk & 15;
    const int t = threadIdx.x;
    const int lane = t & 63, wave = t >> 6;
    const int ql = lane & 15, g = lane >> 4;
    const _Float16* Qp = Q + (size_t)blk * 8192;
    const _Float16* Kp = K + (size_t)blk * 8192;
    const _Float16* Vp = V + (size_t)blk * 8192;
    const _Float16* rp = rpbh + (size_t)h * 65536;
    const _Float16* mp = maskh + (size_t)(b & 63) * 65536;

    // V fragments (B operand of PV): vf[dh][tt][j] = V[tt*16+g*4+j][dh*16+ql]
    half4 vf[2][16];
#pragma unroll
    for (int tt = 0; tt < 16; ++tt) {
#pragma unroll
        for (int dh = 0; dh < 2; ++dh) {
            half4 xv;
#pragma unroll
            for (int j = 0; j < 4; ++j)
                xv[j] = Vp[(size_t)((tt * 16 + g * 4 + j) * 32 + dh * 16 + ql)];
            vf[dh][tt] = xv;
        }
    }

#pragma unroll 1
    for (int qg = 0; qg < 4; ++qg) {
        const int q0 = wave * 64 + qg * 16;
        const int q = q0 + ql;
        half8 qf = *(const half8*)(Qp + (size_t)q * 32 + g * 8);
        f32x4 acc[16];
#pragma unroll
        for (int tt = 0; tt < 16; ++tt) {
            half8 kf = *(const half8*)(Kp + (size_t)(tt * 16 + ql) * 32 + g * 8);
            f32x4 z = { 0.f, 0.f, 0.f, 0.f };
            acc[tt] = __builtin_amdgcn_mfma_f32_16x16x32_f16(kf, qf, z, 0, 0, 0);
        }
        // add relative-position bias + window mask (Q was pre-scaled)
#pragma unroll
        for (int tt = 0; tt < 16; ++tt) {
            half4 rb = *(const half4*)(rp + (size_t)q * 256 + tt * 16 + g * 4);
            half4 mb = *(const half4*)(mp + (size_t)q * 256 + tt * 16 + g * 4);
#pragma unroll
            for (int rr = 0; rr < 4; ++rr)
                acc[tt][rr] += (float)rb[rr] + (float)mb[rr];
        }
        // softmax over keys: 64 in-lane values + 2 shuffles
        float m = -1e30f;
#pragma unroll
        for (int tt = 0; tt < 16; ++tt)
#pragma unroll
            for (int rr = 0; rr < 4; ++rr)
                m = fmaxf(m, acc[tt][rr]);
        m = fmaxf(m, __shfl_xor(m, 16));
        m = fmaxf(m, __shfl_xor(m, 32));
        float l = 0.f;
#pragma unroll
        for (int tt = 0; tt < 16; ++tt)
#pragma unroll
            for (int rr = 0; rr < 4; ++rr) {
                float e = __expf(acc[tt][rr] - m);
                acc[tt][rr] = e;
                l += e;
            }
        l += __shfl_xor(l, 16);
        l += __shfl_xor(l, 32);

        // PV: O[q][d] = sum_k P[q][k] V[k][d]   (unnormalized P)
        f32x4 o0 = { 0.f, 0.f, 0.f, 0.f }, o1 = { 0.f, 0.f, 0.f, 0.f };
#pragma unroll
        for (int tt = 0; tt < 16; ++tt) {
            half4 pf = { (_Float16)acc[tt][0], (_Float16)acc[tt][1],
                         (_Float16)acc[tt][2], (_Float16)acc[tt][3] };
            o0 = __builtin_amdgcn_mfma_f32_16x16x16f16(pf, vf[0][tt], o0, 0, 0, 0);
            o1 = __builtin_amdgcn_mfma_f32_16x16x16f16(pf, vf[1][tt], o1, 0, 0, 0);
        }
        // normalize (denominator lives on lane (row&15)) and write preproj
#pragma unroll
        for (int rr = 0; rr < 4; ++rr) {
            float lr = __shfl(l, g * 4 + rr);
            float inv = 1.0f / lr;
            int row = q0 + g * 4 + rr;
            size_t ob = ((size_t)b * 256 + row) * 512 + h * 32;
            pre[ob + ql] = (_Float16)(o0[rr] * inv);
            pre[ob + 16 + ql] = (_Float16)(o1[rr] * inv);
        }
    }
}

// ---------------- output projection (f16 in, fp32 out) ----------------
__global__ __launch_bounds__(256) void proj_out_kernel(
    const _Float16* __restrict__ pre, const float* __restrict__ wgt,
    const float* __restrict__ bias, float* __restrict__ out)
{
    __shared__ __align__(16) _Float16 As[128 * 64];
    __shared__ __align__(16) _Float16 Ws[128 * 64];
    const int t = threadIdx.x;
    const int lane = t & 63, wave = t >> 6;
    const int ql = lane & 15, g = lane >> 4;
    const int ct = blockIdx.x, rt = blockIdx.y;
    const int wr = (wave >> 1) * 64, wc = (wave & 1) * 64;

    f32x4 acc[4][4] = {};
    const int srr = t >> 4, sc4 = (t & 15) * 4;
    const int arr = t >> 3, ac8 = (t & 7) * 8;
    for (int kk = 0; kk < 8; ++kk) {
        const int k0 = kk * 64;
#pragma unroll
        for (int p = 0; p < 4; ++p) {
            int rr = p * 32 + arr;
            half8 v = *(const half8*)(pre + (size_t)(rt * 128 + rr) * 512 + k0 + ac8);
            *(half8*)((char*)As + rr * 128 + ((ac8 * 2) ^ ((rr & 7) << 4))) = v;
        }
#pragma unroll
        for (int p = 0; p < 8; ++p) {
            int rr = p * 16 + srr;
            float4 wv = *(const float4*)(wgt + (size_t)(ct * 128 + rr) * 512 + k0 + sc4);
            half4 wh = { (_Float16)wv.x, (_Float16)wv.y, (_Float16)wv.z, (_Float16)wv.w };
            *(half4*)((char*)Ws + rr * 128 + ((sc4 * 2) ^ ((rr & 7) << 4))) = wh;
        }
        __syncthreads();
#pragma unroll
        for (int kh = 0; kh < 2; ++kh) {
            half8 af[4], bf[4];
#pragma unroll
            for (int i = 0; i < 4; ++i) {
                int row = wr + i * 16 + ql;
                af[i] = *(const half8*)((const char*)As + row * 128 +
                        ((kh * 64 + g * 16) ^ ((ql & 7) << 4)));
            }
#pragma unroll
            for (int j = 0; j < 4; ++j) {
                int row = wc + j * 16 + ql;
                bf[j] = *(const half8*)((const char*)Ws + row * 128 +
                        ((kh * 64 + g * 16) ^ ((ql & 7) << 4)));
            }
#pragma unroll
            for (int i = 0; i < 4; ++i)
#pragma unroll
                for (int j = 0; j < 4; ++j)
                    acc[i][j] = __builtin_amdgcn_mfma_f32_16x16x32_f16(af[i], bf[j], acc[i][j], 0, 0, 0);
        }
        __syncthreads();
    }
#pragma unroll
    for (int j = 0; j < 4; ++j) {
        int c = ct * 128 + wc + j * 16 + ql;
        float bv = bias[c];
#pragma unroll
        for (int i = 0; i < 4; ++i)
#pragma unroll
            for (int rr = 0; rr < 4; ++rr) {
                int r = rt * 128 + wr + i * 16 + g * 4 + rr;
                out[(size_t)r * 512 + c] = acc[i][j][rr] + bv;
            }
    }
}

extern "C" void kernel_launch(void* const* d_in, const int* in_sizes, int n_in,
                              void* d_out, int out_size, void* d_ws, size_t ws_size,
                              hipStream_t stream)
{
    const float* x      = (const float*)d_in[0];
    const float* y      = (const float*)d_in[1];
    const float* mask   = (const float*)d_in[2];
    const float* q_w    = (const float*)d_in[3];
    const float* q_b    = (const float*)d_in[4];
    const float* kv_w   = (const float*)d_in[5];
    const float* kv_b   = (const float*)d_in[6];
    const float* proj_w = (const float*)d_in[7];
    const float* proj_b = (const float*)d_in[8];
    const float* btab   = (const float*)d_in[9];
    const int*   rpi    = (const int*)d_in[10];
    float* out = (float*)d_out;

    char* ws = (char*)d_ws;
    _Float16* Qw  = (_Float16*)(ws);                                  // 64 MiB
    _Float16* Kw  = (_Float16*)(ws + ((size_t)64 << 20));             // 64 MiB
    _Float16* Vw  = (_Float16*)(ws + ((size_t)128 << 20));            // 64 MiB
    _Float16* Pre = (_Float16*)(ws + ((size_t)192 << 20));            // 64 MiB
    _Float16* Rpb = (_Float16*)(ws + ((size_t)256 << 20));            // 2 MiB
    _Float16* Mh  = (_Float16*)(ws + ((size_t)256 << 20) + 2097152);  // 8 MiB

    prep_kernel<<<4096, 256, 0, stream>>>(mask, btab, rpi, Mh, Rpb);
    proj_qkv<<<dim3(4, 512), 256, 0, stream>>>(x, q_w, q_b, Qw, Kw, Vw, 0);
    proj_qkv<<<dim3(8, 512), 256, 0, stream>>>(y, kv_w, kv_b, Qw, Kw, Vw, 1);
    attn_kernel<<<4096, 256, 0, stream>>>(Qw, Kw, Vw, Rpb, Mh, Pre);
    proj_out_kernel<<<dim3(4, 512), 256, 0, stream>>>(Pre, proj_w, proj_b, out);
}